// Round 3
// baseline (325.852 us; speedup 1.0000x reference)
//
#include <hip/hip_runtime.h>

#define NC 4  // cells per thread

__device__ __forceinline__ float tanh_fast(float x) {
    // tanh(x) = 1 - 2/(exp(2x)+1);  exp(2x) = exp2(2*log2(e)*x)
    float e = exp2f(x * 2.8853900817779268f);
    return 1.0f - 2.0f * __builtin_amdgcn_rcpf(e + 1.0f);
}

__global__ __launch_bounds__(256) void riemann_kernel(
    const float* __restrict__ P, const float* __restrict__ U,
    const float* __restrict__ F, const float* __restrict__ cmax,
    const float* __restrict__ cmin,
    const float* __restrict__ W1_ds, const float* __restrict__ b1_ds,
    const float* __restrict__ W2_ds, const float* __restrict__ b2_ds,
    const float* __restrict__ W1_dr, const float* __restrict__ b1_dr,
    const float* __restrict__ W2_dr, const float* __restrict__ b2_dr,
    const float* __restrict__ W1_rs, const float* __restrict__ b1_rs,
    const float* __restrict__ W2_rs, const float* __restrict__ b2_rs,
    float* __restrict__ out, int N) {
    int t = blockIdx.x * blockDim.x + threadIdx.x;
    int base = t * NC;
    if (base >= N) return;

    // ---- bulk-load NC cells: P/U/F are 6 floats/cell, contiguous ----
    float rawP[6 * NC], rawU[6 * NC], rawF[6 * NC], cmv[NC], cnv[NC];
    {
        const float4* P4 = (const float4*)(P + (size_t)base * 6);
        const float4* U4 = (const float4*)(U + (size_t)base * 6);
        const float4* F4 = (const float4*)(F + (size_t)base * 6);
#pragma unroll
        for (int q = 0; q < 6 * NC / 4; ++q) {
            ((float4*)rawP)[q] = P4[q];
            ((float4*)rawU)[q] = U4[q];
            ((float4*)rawF)[q] = F4[q];
        }
        float4 cm4 = *(const float4*)(cmax + base);
        float4 cn4 = *(const float4*)(cmin + base);
        cmv[0] = cm4.x; cmv[1] = cm4.y; cmv[2] = cm4.z; cmv[3] = cm4.w;
        cnv[0] = cn4.x; cnv[1] = cn4.y; cnv[2] = cn4.z; cnv[3] = cn4.w;
    }

    // ---- per-cell: flip, features, HLLE, f64 classification ----
    float fe[NC][20];        // Pf(6), Uf(6), Ff(6), cmax, cmin
    float hl[NC][3];
    int   label[NC];
    bool  cont[NC], flip[NC];

#pragma unroll
    for (int c = 0; c < NC; ++c) {
        const float* Pr = rawP + c * 6;
        const float* Ur = rawU + c * 6;
        const float* Fr = rawF + c * 6;
        bool fl = Pr[3] > Pr[2];   // P[1][1] > P[1][0]
        flip[c] = fl;
        // sgn = {1,1,-1}; F uses -sgn
        fe[c][0]  = fl ?  Pr[1] :  Pr[0];
        fe[c][1]  = fl ?  Pr[0] :  Pr[1];
        fe[c][2]  = fl ?  Pr[3] :  Pr[2];
        fe[c][3]  = fl ?  Pr[2] :  Pr[3];
        fe[c][4]  = fl ? -Pr[5] :  Pr[4];
        fe[c][5]  = fl ? -Pr[4] :  Pr[5];
        fe[c][6]  = fl ?  Ur[1] :  Ur[0];
        fe[c][7]  = fl ?  Ur[0] :  Ur[1];
        fe[c][8]  = fl ?  Ur[3] :  Ur[2];
        fe[c][9]  = fl ?  Ur[2] :  Ur[3];
        fe[c][10] = fl ? -Ur[5] :  Ur[4];
        fe[c][11] = fl ? -Ur[4] :  Ur[5];
        fe[c][12] = fl ? -Fr[1] : -0.0f * 0.0f + Fr[0];
        fe[c][12] = fl ? -Fr[1] :  Fr[0];
        fe[c][13] = fl ? -Fr[0] :  Fr[1];
        fe[c][14] = fl ? -Fr[3] :  Fr[2];
        fe[c][15] = fl ? -Fr[2] :  Fr[3];
        fe[c][16] = fl ?  Fr[5] :  Fr[4];
        fe[c][17] = fl ?  Fr[4] :  Fr[5];
        fe[c][18] = cmv[c];
        fe[c][19] = cnv[c];

        // HLLE (f32, continuous)
        float cmf = cmv[c], cnf = cnv[c];
        float inv = 1.0f / (cmf - cnf);
        float cmn = cmf * cnf;
        hl[c][0] = (cmf * fe[c][12] - cnf * fe[c][13] + cmn * (fe[c][7]  - fe[c][6]))  * inv;
        hl[c][1] = (cmf * fe[c][14] - cnf * fe[c][15] + cmn * (fe[c][9]  - fe[c][8]))  * inv;
        hl[c][2] = (cmf * fe[c][16] - cnf * fe[c][17] + cmn * (fe[c][11] - fe[c][10])) * inv;

        // discrete decisions in f64 (knife-edge safety vs np-f64 reference)
        double rho0 = (double)fe[c][0], rho1 = (double)fe[c][1];
        double p0   = (double)fe[c][2], p1   = (double)fe[c][3];
        double v0   = (double)fe[c][4], v1   = (double)fe[c][5];
        const double g = 5.0 / 3.0;

        double dd0 = fabs(rho1 - rho0);
        double dd1 = fabs(p1 - p0);
        double dd2 = fabs(v1 - v0);
        cont[c] = fmax(fmax(dd0, dd1), dd2) < 0.005;

        double c0 = sqrt(g * p0 / rho0);
        double c1 = sqrt(g * p1 / rho1);
        double dv = v1 - v0;
        double z = (g - 1.0) / (2.0 * g);
        double num = c0 + c1 - 0.5 * (g - 1.0) * dv;
        double den = c0 / pow(p0, z) + c1 / pow(p1, z);
        double ps = pow(fmax(num / den, 1e-8), 1.0 / z);
        bool vac = dv >= 2.0 / (g - 1.0) * (c0 + c1);
        bool drb = ps < fmin(p0, p1);
        bool dsb = ps > fmax(p0, p1);
        label[c] = vac ? 3 : (drb ? 1 : (dsb ? 0 : 2));
    }

    // ---- three MLPs; j in groups of 4 so weight loads are float4 ----
    float o[NC][3];
#pragma unroll
    for (int c = 0; c < NC; ++c) { o[c][0] = 0.0f; o[c][1] = 0.0f; o[c][2] = 0.0f; }

#pragma unroll 1
    for (int m = 0; m < 3; ++m) {
        const float* W1 = (m == 0) ? W1_ds : ((m == 1) ? W1_dr : W1_rs);
        const float* b1 = (m == 0) ? b1_ds : ((m == 1) ? b1_dr : b1_rs);
        const float* W2 = (m == 0) ? W2_ds : ((m == 1) ? W2_dr : W2_rs);
        const float* b2 = (m == 0) ? b2_ds : ((m == 1) ? b2_dr : b2_rs);

        float acc[NC][3];
        float b20 = b2[0], b21 = b2[1], b22 = b2[2];
#pragma unroll
        for (int c = 0; c < NC; ++c) { acc[c][0] = b20; acc[c][1] = b21; acc[c][2] = b22; }

#pragma unroll 1
        for (int jg = 0; jg < 64; jg += 4) {
            float4 b1v = *(const float4*)(b1 + jg);
            float h[NC][4];
#pragma unroll
            for (int c = 0; c < NC; ++c) {
                h[c][0] = b1v.x; h[c][1] = b1v.y; h[c][2] = b1v.z; h[c][3] = b1v.w;
            }
#pragma unroll
            for (int k = 0; k < 20; ++k) {
                float4 w = *(const float4*)(W1 + k * 64 + jg);
#pragma unroll
                for (int c = 0; c < NC; ++c) {
                    float f = fe[c][k];
                    h[c][0] = fmaf(f, w.x, h[c][0]);
                    h[c][1] = fmaf(f, w.y, h[c][1]);
                    h[c][2] = fmaf(f, w.z, h[c][2]);
                    h[c][3] = fmaf(f, w.w, h[c][3]);
                }
            }
            // W2 rows jg..jg+3 = 12 contiguous floats (16B-aligned: jg%4==0)
            float w2v[12];
            ((float4*)w2v)[0] = *(const float4*)(W2 + jg * 3);
            ((float4*)w2v)[1] = *(const float4*)(W2 + jg * 3 + 4);
            ((float4*)w2v)[2] = *(const float4*)(W2 + jg * 3 + 8);
#pragma unroll
            for (int c = 0; c < NC; ++c) {
#pragma unroll
                for (int jj = 0; jj < 4; ++jj) {
                    float tv = tanh_fast(h[c][jj]);
                    acc[c][0] = fmaf(tv, w2v[jj * 3 + 0], acc[c][0]);
                    acc[c][1] = fmaf(tv, w2v[jj * 3 + 1], acc[c][1]);
                    acc[c][2] = fmaf(tv, w2v[jj * 3 + 2], acc[c][2]);
                }
            }
        }
#pragma unroll
        for (int c = 0; c < NC; ++c) {
            if (label[c] == m) { o[c][0] = acc[c][0]; o[c][1] = acc[c][1]; o[c][2] = acc[c][2]; }
        }
    }

    // ---- contact override, un-flip, store (12 contiguous floats) ----
    float outv[3 * NC];
#pragma unroll
    for (int c = 0; c < NC; ++c) {
        float o0 = o[c][0], o1 = o[c][1], o2 = o[c][2];
        if (cont[c]) { o0 = hl[c][0]; o1 = hl[c][1]; o2 = hl[c][2]; }
        if (flip[c]) { o0 = -o0; o1 = -o1; }
        outv[c * 3 + 0] = o0;
        outv[c * 3 + 1] = o1;
        outv[c * 3 + 2] = o2;
    }
    float4* out4 = (float4*)(out + (size_t)base * 3);
#pragma unroll
    for (int q = 0; q < 3 * NC / 4; ++q) out4[q] = ((float4*)outv)[q];
}

extern "C" void kernel_launch(void* const* d_in, const int* in_sizes, int n_in,
                              void* d_out, int out_size, void* d_ws, size_t ws_size,
                              hipStream_t stream) {
    const float* P     = (const float*)d_in[0];
    const float* U     = (const float*)d_in[1];
    const float* F     = (const float*)d_in[2];
    const float* cmax  = (const float*)d_in[3];
    const float* cmin  = (const float*)d_in[4];
    const float* W1_ds = (const float*)d_in[5];
    const float* b1_ds = (const float*)d_in[6];
    const float* W2_ds = (const float*)d_in[7];
    const float* b2_ds = (const float*)d_in[8];
    const float* W1_dr = (const float*)d_in[9];
    const float* b1_dr = (const float*)d_in[10];
    const float* W2_dr = (const float*)d_in[11];
    const float* b2_dr = (const float*)d_in[12];
    const float* W1_rs = (const float*)d_in[13];
    const float* b1_rs = (const float*)d_in[14];
    const float* W2_rs = (const float*)d_in[15];
    const float* b2_rs = (const float*)d_in[16];

    int N = in_sizes[3];  // cmax has N elements
    float* out = (float*)d_out;

    int threads = (N + NC - 1) / NC;
    dim3 block(256);
    dim3 grid((threads + 255) / 256);
    hipLaunchKernelGGL(riemann_kernel, grid, block, 0, stream,
                       P, U, F, cmax, cmin,
                       W1_ds, b1_ds, W2_ds, b2_ds,
                       W1_dr, b1_dr, W2_dr, b2_dr,
                       W1_rs, b1_rs, W2_rs, b2_rs,
                       out, N);
}

// Round 4
// 304.029 us; speedup vs baseline: 1.0718x; 1.0718x over previous
//
#include <hip/hip_runtime.h>

__device__ __forceinline__ float tanh_fast(float x) {
    // tanh(x) = 1 - 2/(exp(2x)+1);  exp(2x) = exp2(2*log2(e)*x)
    float e = exp2f(x * 2.8853900817779268f);
    float r = __builtin_amdgcn_rcpf(e + 1.0f);
    return fmaf(-2.0f, r, 1.0f);
}

__global__ __launch_bounds__(256) void riemann_kernel(
    const float* __restrict__ P, const float* __restrict__ U,
    const float* __restrict__ F, const float* __restrict__ cmax,
    const float* __restrict__ cmin,
    const float* __restrict__ W1_ds, const float* __restrict__ b1_ds,
    const float* __restrict__ W2_ds, const float* __restrict__ b2_ds,
    const float* __restrict__ W1_dr, const float* __restrict__ b1_dr,
    const float* __restrict__ W2_dr, const float* __restrict__ b2_dr,
    const float* __restrict__ W1_rs, const float* __restrict__ b1_rs,
    const float* __restrict__ W2_rs, const float* __restrict__ b2_rs,
    float* __restrict__ out, int N) {
    int i = blockIdx.x * blockDim.x + threadIdx.x;
    if (i >= N) return;

    // ---- load P,U,F (3x2 row-major per cell = 6 consecutive floats) ----
    const float2* P2 = (const float2*)P + (size_t)i * 3;
    const float2* U2 = (const float2*)U + (size_t)i * 3;
    const float2* F2 = (const float2*)F + (size_t)i * 3;
    float2 Pa = P2[0], Pb = P2[1], Pc = P2[2];
    float2 Ua = U2[0], Ub = U2[1], Uc = U2[2];
    float2 Fa = F2[0], Fb = F2[1], Fc = F2[2];
    float cm = cmax[i];
    float cn = cmin[i];

    // ---- flip: P[1][1] > P[1][0] (sgn = {1,1,-1}; F uses -sgn) ----
    bool flip = Pb.y > Pb.x;
    float pf0 = flip ?  Pa.y :  Pa.x;   // rho L
    float pf1 = flip ?  Pa.x :  Pa.y;   // rho R
    float pf2 = flip ?  Pb.y :  Pb.x;   // p   L
    float pf3 = flip ?  Pb.x :  Pb.y;   // p   R
    float pf4 = flip ? -Pc.y :  Pc.x;   // v   L
    float pf5 = flip ? -Pc.x :  Pc.y;   // v   R

    float uf0 = flip ?  Ua.y :  Ua.x;
    float uf1 = flip ?  Ua.x :  Ua.y;
    float uf2 = flip ?  Ub.y :  Ub.x;
    float uf3 = flip ?  Ub.x :  Ub.y;
    float uf4 = flip ? -Uc.y :  Uc.x;
    float uf5 = flip ? -Uc.x :  Uc.y;

    float ff0 = flip ? -Fa.y :  Fa.x;
    float ff1 = flip ? -Fa.x :  Fa.y;
    float ff2 = flip ? -Fb.y :  Fb.x;
    float ff3 = flip ? -Fb.x :  Fb.y;
    float ff4 = flip ?  Fc.y :  Fc.x;
    float ff5 = flip ?  Fc.x :  Fc.y;

    // ---- cont: exact f64 compares (f32->f64 exact; diffs exact in f64) ----
    {
    }
    double dd0 = fabs((double)pf1 - (double)pf0);
    double dd1 = fabs((double)pf3 - (double)pf2);
    double dd2 = fabs((double)pf5 - (double)pf4);
    bool cont = fmax(fmax(dd0, dd1), dd2) < 0.005;

    // ---- HLLE flux (f32, continuous -> threshold-safe) ----
    float inv = 1.0f / (cm - cn);
    float cmn = cm * cn;
    float h0 = (cm * ff0 - cn * ff1 + cmn * (uf1 - uf0)) * inv;
    float h1 = (cm * ff2 - cn * ff3 + cmn * (uf3 - uf2)) * inv;
    float h2 = (cm * ff4 - cn * ff5 + cmn * (uf5 - uf4)) * inv;

    // ---- classification: f32 fast path + epsilon-guarded f64 fallback ----
    float c0f = sqrtf(1.6666666f * pf2 / pf0);
    float c1f = sqrtf(1.6666666f * pf3 / pf1);
    float dvf = pf5 - pf4;
    float numf = c0f + c1f - (1.0f / 3.0f) * dvf;
    float pz0 = exp2f(-0.2f * log2f(pf2));          // p0^-z, z=0.2
    float pz1 = exp2f(-0.2f * log2f(pf3));
    float denf = c0f * pz0 + c1f * pz1;
    float tq = fmaxf(numf / denf, 1e-8f);
    float t2 = tq * tq;
    float psf = t2 * t2 * tq;                        // tq^5
    float pminf = fminf(pf2, pf3);
    float pmaxf = fmaxf(pf2, pf3);
    float csum3 = 3.0f * (c0f + c1f);
    float vs = dvf - csum3;                          // vacuum margin
    bool vac = vs >= 0.0f;
    int label = vac ? 3 : (psf < pminf ? 1 : (psf > pmaxf ? 0 : 2));

    const float eps = 2e-4f;
    bool amb = (fabsf(psf - pminf) <= eps * pminf) ||
               (fabsf(psf - pmaxf) <= eps * pmaxf) ||
               (fabsf(vs) <= eps * (fabsf(dvf) + csum3));
    if (__builtin_expect(amb, 0)) {
        // exact f64 replication of the np reference (executes for ~1e-4 of cells)
        double rho0 = (double)pf0, rho1 = (double)pf1;
        double p0   = (double)pf2, p1   = (double)pf3;
        double v0   = (double)pf4, v1   = (double)pf5;
        const double g = 5.0 / 3.0;
        double c0 = sqrt(g * p0 / rho0);
        double c1 = sqrt(g * p1 / rho1);
        double dv = v1 - v0;
        double z = (g - 1.0) / (2.0 * g);
        double num = c0 + c1 - 0.5 * (g - 1.0) * dv;
        double den = c0 / pow(p0, z) + c1 / pow(p1, z);
        double ps = pow(fmax(num / den, 1e-8), 1.0 / z);
        bool vacd = dv >= 2.0 / (g - 1.0) * (c0 + c1);
        bool drb = ps < fmin(p0, p1);
        bool dsb = ps > fmax(p0, p1);
        label = vacd ? 3 : (drb ? 1 : (dsb ? 0 : 2));
    }

    // ---- features (Pf,Uf,Ff row-major, cmax, cmin) ----
    float fe[20] = {pf0, pf1, pf2, pf3, pf4, pf5,
                    uf0, uf1, uf2, uf3, uf4, uf5,
                    ff0, ff1, ff2, ff3, ff4, ff5,
                    cm,  cn};

    // ---- three MLPs; j in groups of 4 -> float4 weight loads ----
    float o0 = 0.0f, o1 = 0.0f, o2 = 0.0f;
#pragma unroll 1
    for (int m = 0; m < 3; ++m) {
        const float* W1 = (m == 0) ? W1_ds : ((m == 1) ? W1_dr : W1_rs);
        const float* b1 = (m == 0) ? b1_ds : ((m == 1) ? b1_dr : b1_rs);
        const float* W2 = (m == 0) ? W2_ds : ((m == 1) ? W2_dr : W2_rs);
        const float* b2 = (m == 0) ? b2_ds : ((m == 1) ? b2_dr : b2_rs);

        float a0 = b2[0], a1 = b2[1], a2 = b2[2];
#pragma unroll 1
        for (int jg = 0; jg < 64; jg += 4) {
            float4 b1v = *(const float4*)(b1 + jg);
            float hh0 = b1v.x, hh1 = b1v.y, hh2 = b1v.z, hh3 = b1v.w;
#pragma unroll
            for (int k = 0; k < 20; ++k) {
                float4 w = *(const float4*)(W1 + k * 64 + jg);
                float f = fe[k];
                hh0 = fmaf(f, w.x, hh0);
                hh1 = fmaf(f, w.y, hh1);
                hh2 = fmaf(f, w.z, hh2);
                hh3 = fmaf(f, w.w, hh3);
            }
            // W2 rows jg..jg+3 = 12 contiguous floats (jg%4==0 -> 16B aligned)
            float4 w2a = *(const float4*)(W2 + jg * 3);
            float4 w2b = *(const float4*)(W2 + jg * 3 + 4);
            float4 w2c = *(const float4*)(W2 + jg * 3 + 8);
            float tv0 = tanh_fast(hh0);
            float tv1 = tanh_fast(hh1);
            float tv2 = tanh_fast(hh2);
            float tv3 = tanh_fast(hh3);
            a0 = fmaf(tv0, w2a.x, a0); a1 = fmaf(tv0, w2a.y, a1); a2 = fmaf(tv0, w2a.z, a2);
            a0 = fmaf(tv1, w2a.w, a0); a1 = fmaf(tv1, w2b.x, a1); a2 = fmaf(tv1, w2b.y, a2);
            a0 = fmaf(tv2, w2b.z, a0); a1 = fmaf(tv2, w2b.w, a1); a2 = fmaf(tv2, w2c.x, a2);
            a0 = fmaf(tv3, w2c.y, a0); a1 = fmaf(tv3, w2c.z, a1); a2 = fmaf(tv3, w2c.w, a2);
        }
        if (label == m) { o0 = a0; o1 = a1; o2 = a2; }
    }

    // ---- contact override, then un-flip (flux * -sgn = {-,-,+}) ----
    if (cont) { o0 = h0; o1 = h1; o2 = h2; }
    if (flip) { o0 = -o0; o1 = -o1; }

    out[(size_t)i * 3 + 0] = o0;
    out[(size_t)i * 3 + 1] = o1;
    out[(size_t)i * 3 + 2] = o2;
}

extern "C" void kernel_launch(void* const* d_in, const int* in_sizes, int n_in,
                              void* d_out, int out_size, void* d_ws, size_t ws_size,
                              hipStream_t stream) {
    const float* P     = (const float*)d_in[0];
    const float* U     = (const float*)d_in[1];
    const float* F     = (const float*)d_in[2];
    const float* cmax  = (const float*)d_in[3];
    const float* cmin  = (const float*)d_in[4];
    const float* W1_ds = (const float*)d_in[5];
    const float* b1_ds = (const float*)d_in[6];
    const float* W2_ds = (const float*)d_in[7];
    const float* b2_ds = (const float*)d_in[8];
    const float* W1_dr = (const float*)d_in[9];
    const float* b1_dr = (const float*)d_in[10];
    const float* W2_dr = (const float*)d_in[11];
    const float* b2_dr = (const float*)d_in[12];
    const float* W1_rs = (const float*)d_in[13];
    const float* b1_rs = (const float*)d_in[14];
    const float* W2_rs = (const float*)d_in[15];
    const float* b2_rs = (const float*)d_in[16];

    int N = in_sizes[3];  // cmax has N elements
    float* out = (float*)d_out;

    dim3 block(256);
    dim3 grid((N + 255) / 256);
    hipLaunchKernelGGL(riemann_kernel, grid, block, 0, stream,
                       P, U, F, cmax, cmin,
                       W1_ds, b1_ds, W2_ds, b2_ds,
                       W1_dr, b1_dr, W2_dr, b2_dr,
                       W1_rs, b1_rs, W2_rs, b2_rs,
                       out, N);
}

// Round 6
// 251.116 us; speedup vs baseline: 1.2976x; 1.2107x over previous
//
#include <hip/hip_runtime.h>
#include <cstdint>

typedef __attribute__((ext_vector_type(8))) short bf16x8;
typedef __attribute__((ext_vector_type(4))) float f32x4;

__device__ __forceinline__ uint32_t bf16_rne(float f) {
    uint32_t u = __float_as_uint(f);
    u += 0x7FFFu + ((u >> 16) & 1u);
    return u >> 16;
}
__device__ __forceinline__ float bf16_f32(uint32_t h) {
    return __uint_as_float(h << 16);
}

__device__ __forceinline__ float tanh_fast(float x) {
    // tanh(x) = 1 - 2/(exp2(2*log2e*x)+1); raw HW trans ops
    float e = __builtin_amdgcn_exp2f(x * 2.8853900817779268f);
    return fmaf(-2.0f, __builtin_amdgcn_rcpf(e + 1.0f), 1.0f);
}

__device__ __forceinline__ float sel4(float a, float b, float c, float d, int T) {
    float x = (T & 1) ? b : a;
    float y = (T & 1) ? d : c;
    return (T & 2) ? y : x;
}

// ---- prep: W1 (20x64 k-major) -> MFMA A-frag layout, split bf16 hi+lo ----
// owner (m,Ht,lane): A[row=(lane&15)+16*Ht][k=(lane>>4)*8+j], j=0..7; k>=20 -> 0
// hi frags at wf[0..3071] (words), lo frags at wf[3072..6143]
__global__ __launch_bounds__(256) void prep_kernel(
    const float* __restrict__ W1_0, const float* __restrict__ W1_1,
    const float* __restrict__ W1_2, uint32_t* __restrict__ wf) {
    int m = blockIdx.x;
    const float* W1 = (m == 0) ? W1_0 : (m == 1) ? W1_1 : W1_2;
    int tid = threadIdx.x;
    int Ht = tid >> 6, lane = tid & 63;
    int n = (lane & 15) + 16 * Ht;
    int kb = (lane >> 4) * 8;
    uint32_t dh[4], dl[4];
#pragma unroll
    for (int q = 0; q < 4; ++q) {
        int k0 = kb + 2 * q, k1 = k0 + 1;
        float w0 = (k0 < 20) ? W1[k0 * 64 + n] : 0.0f;
        float w1 = (k1 < 20) ? W1[k1 * 64 + n] : 0.0f;
        uint32_t h0 = bf16_rne(w0), h1 = bf16_rne(w1);
        uint32_t l0 = bf16_rne(w0 - bf16_f32(h0));
        uint32_t l1 = bf16_rne(w1 - bf16_f32(h1));
        dh[q] = h0 | (h1 << 16);
        dl[q] = l0 | (l1 << 16);
    }
    size_t idx = ((size_t)(m * 4 + Ht) * 64 + lane) * 4;
    *(uint4*)(wf + idx)        = make_uint4(dh[0], dh[1], dh[2], dh[3]);
    *(uint4*)(wf + 3072 + idx) = make_uint4(dl[0], dl[1], dl[2], dl[3]);
}

__global__ __launch_bounds__(256) void riemann_mfma(
    const float* __restrict__ P, const float* __restrict__ U,
    const float* __restrict__ F, const float* __restrict__ cmax,
    const float* __restrict__ cmin,
    const float* __restrict__ b1_ds, const float* __restrict__ W2_ds, const float* __restrict__ b2_ds,
    const float* __restrict__ b1_dr, const float* __restrict__ W2_dr, const float* __restrict__ b2_dr,
    const float* __restrict__ b1_rs, const float* __restrict__ W2_rs, const float* __restrict__ b2_rs,
    const uint32_t* __restrict__ wf,
    float* __restrict__ out, int N) {
    __shared__ __align__(16) uint32_t lds_hi[4][64][20];  // 80B row stride
    __shared__ __align__(16) uint32_t lds_lo[4][64][20];
    __shared__ int lds_lab[256];

    int tid = threadIdx.x;
    int wv = tid >> 6, lane = tid & 63;
    int hi = lane >> 4, lo16 = lane & 15;
    int cell = blockIdx.x * 256 + tid;
    int cg = cell < N ? cell : N - 1;

    // ---- per-cell prologue ----
    const float2* P2 = (const float2*)P + (size_t)cg * 3;
    const float2* U2 = (const float2*)U + (size_t)cg * 3;
    const float2* F2 = (const float2*)F + (size_t)cg * 3;
    float2 Pa = P2[0], Pb = P2[1], Pc = P2[2];
    float2 Ua = U2[0], Ub = U2[1], Uc = U2[2];
    float2 Fa = F2[0], Fb = F2[1], Fc = F2[2];
    float cm = cmax[cg];
    float cn = cmin[cg];

    bool flip = Pb.y > Pb.x;
    float fe[20];
    fe[0]  = flip ?  Pa.y :  Pa.x;
    fe[1]  = flip ?  Pa.x :  Pa.y;
    fe[2]  = flip ?  Pb.y :  Pb.x;
    fe[3]  = flip ?  Pb.x :  Pb.y;
    fe[4]  = flip ? -Pc.y :  Pc.x;
    fe[5]  = flip ? -Pc.x :  Pc.y;
    fe[6]  = flip ?  Ua.y :  Ua.x;
    fe[7]  = flip ?  Ua.x :  Ua.y;
    fe[8]  = flip ?  Ub.y :  Ub.x;
    fe[9]  = flip ?  Ub.x :  Ub.y;
    fe[10] = flip ? -Uc.y :  Uc.x;
    fe[11] = flip ? -Uc.x :  Uc.y;
    fe[12] = flip ? -Fa.y :  Fa.x;
    fe[13] = flip ? -Fa.x :  Fa.y;
    fe[14] = flip ? -Fb.y :  Fb.x;
    fe[15] = flip ? -Fb.x :  Fb.y;
    fe[16] = flip ?  Fc.y :  Fc.x;
    fe[17] = flip ?  Fc.x :  Fc.y;
    fe[18] = cm;
    fe[19] = cn;

    // cont: exact f64 compares
    double dd0 = fabs((double)fe[1] - (double)fe[0]);
    double dd1 = fabs((double)fe[3] - (double)fe[2]);
    double dd2 = fabs((double)fe[5] - (double)fe[4]);
    bool cont = fmax(fmax(dd0, dd1), dd2) < 0.005;

    // HLLE (f32)
    float inv = __builtin_amdgcn_rcpf(cm - cn);
    float cmn = cm * cn;
    float hl0 = (cm * fe[12] - cn * fe[13] + cmn * (fe[7]  - fe[6]))  * inv;
    float hl1 = (cm * fe[14] - cn * fe[15] + cmn * (fe[9]  - fe[8]))  * inv;
    float hl2 = (cm * fe[16] - cn * fe[17] + cmn * (fe[11] - fe[10])) * inv;

    // classification: f32 fast path + eps-guarded exact f64 fallback
    float c0f = __builtin_amdgcn_sqrtf(1.6666666f * fe[2] * __builtin_amdgcn_rcpf(fe[0]));
    float c1f = __builtin_amdgcn_sqrtf(1.6666666f * fe[3] * __builtin_amdgcn_rcpf(fe[1]));
    float dvf = fe[5] - fe[4];
    float numf = c0f + c1f - (1.0f / 3.0f) * dvf;
    float pz0 = __builtin_amdgcn_exp2f(-0.2f * __builtin_amdgcn_logf(fe[2]));
    float pz1 = __builtin_amdgcn_exp2f(-0.2f * __builtin_amdgcn_logf(fe[3]));
    float denf = c0f * pz0 + c1f * pz1;
    float tq = fmaxf(numf * __builtin_amdgcn_rcpf(denf), 1e-8f);
    float t2 = tq * tq;
    float psf = t2 * t2 * tq;
    float pminf = fminf(fe[2], fe[3]);
    float pmaxf = fmaxf(fe[2], fe[3]);
    float csum3 = 3.0f * (c0f + c1f);
    float vs = dvf - csum3;
    int label = (vs >= 0.0f) ? 3 : (psf < pminf ? 1 : (psf > pmaxf ? 0 : 2));

    const float eps = 2e-4f;
    bool amb = (fabsf(psf - pminf) <= eps * pminf) ||
               (fabsf(psf - pmaxf) <= eps * pmaxf) ||
               (fabsf(vs) <= eps * (fabsf(dvf) + csum3));
    if (__builtin_expect(amb, 0)) {
        double rho0 = (double)fe[0], rho1 = (double)fe[1];
        double p0   = (double)fe[2], p1   = (double)fe[3];
        double v0   = (double)fe[4], v1   = (double)fe[5];
        const double g = 5.0 / 3.0;
        double c0 = sqrt(g * p0 / rho0);
        double c1 = sqrt(g * p1 / rho1);
        double dv = v1 - v0;
        double z = (g - 1.0) / (2.0 * g);
        double num = c0 + c1 - 0.5 * (g - 1.0) * dv;
        double den = c0 / pow(p0, z) + c1 / pow(p1, z);
        double ps = pow(fmax(num / den, 1e-8), 1.0 / z);
        bool vacd = dv >= 2.0 / (g - 1.0) * (c0 + c1);
        label = vacd ? 3 : (ps < fmin(p0, p1) ? 1 : (ps > fmax(p0, p1) ? 0 : 2));
    }

    // ---- stage feats, split bf16 hi+lo, k-contiguous, zero-padded to 32 ----
    uint32_t pkh[10], pkl[10];
#pragma unroll
    for (int q = 0; q < 10; ++q) {
        float f0 = fe[2 * q], f1 = fe[2 * q + 1];
        uint32_t h0 = bf16_rne(f0), h1 = bf16_rne(f1);
        uint32_t l0 = bf16_rne(f0 - bf16_f32(h0));
        uint32_t l1 = bf16_rne(f1 - bf16_f32(h1));
        pkh[q] = h0 | (h1 << 16);
        pkl[q] = l0 | (l1 << 16);
    }
    uint32_t* rowh = lds_hi[wv][lane];
    uint32_t* rowl = lds_lo[wv][lane];
    *(uint4*)(rowh)      = make_uint4(pkh[0], pkh[1], pkh[2], pkh[3]);
    *(uint4*)(rowh + 4)  = make_uint4(pkh[4], pkh[5], pkh[6], pkh[7]);
    *(uint4*)(rowh + 8)  = make_uint4(pkh[8], pkh[9], 0u, 0u);
    *(uint4*)(rowh + 12) = make_uint4(0u, 0u, 0u, 0u);
    *(uint4*)(rowl)      = make_uint4(pkl[0], pkl[1], pkl[2], pkl[3]);
    *(uint4*)(rowl + 4)  = make_uint4(pkl[4], pkl[5], pkl[6], pkl[7]);
    *(uint4*)(rowl + 8)  = make_uint4(pkl[8], pkl[9], 0u, 0u);
    *(uint4*)(rowl + 12) = make_uint4(0u, 0u, 0u, 0u);
    lds_lab[tid] = label;
    __syncthreads();

    // ---- B-frags (hi+lo): lane holds B[k=hi*8+j][cell=lo16+16Ct] ----
    bf16x8 bfh[4], bfl[4];
    int lbl[4];
#pragma unroll
    for (int Ct = 0; Ct < 4; ++Ct) {
        const char* bh = (const char*)lds_hi[wv][lo16 + 16 * Ct];
        const char* bl = (const char*)lds_lo[wv][lo16 + 16 * Ct];
        bfh[Ct] = *(const bf16x8*)(bh + hi * 16);
        bfl[Ct] = *(const bf16x8*)(bl + hi * 16);
        lbl[Ct] = lds_lab[wv * 64 + lo16 + 16 * Ct];
    }

    float out_acc[4][3];
#pragma unroll
    for (int Ct = 0; Ct < 4; ++Ct) { out_acc[Ct][0] = 0.f; out_acc[Ct][1] = 0.f; out_acc[Ct][2] = 0.f; }

#pragma unroll 1
    for (int m = 0; m < 3; ++m) {
        const float* b1 = (m == 0) ? b1_ds : (m == 1) ? b1_dr : b1_rs;
        const float* W2 = (m == 0) ? W2_ds : (m == 1) ? W2_dr : W2_rs;

        bf16x8 afh[4], afl[4];
        f32x4 b1v[4];
        float w2v[4][12];
#pragma unroll
        for (int Ht = 0; Ht < 4; ++Ht) {
            size_t idx = (size_t)((m * 4 + Ht) * 64 + lane);
            uint4 wh = ((const uint4*)wf)[idx];
            uint4 wl = ((const uint4*)(wf + 3072))[idx];
            afh[Ht] = __builtin_bit_cast(bf16x8, wh);
            afl[Ht] = __builtin_bit_cast(bf16x8, wl);
            b1v[Ht] = *(const f32x4*)(b1 + 16 * Ht + 4 * hi);
            const float* w2p = W2 + (16 * Ht + 4 * hi) * 3;
            *(float4*)&w2v[Ht][0] = *(const float4*)(w2p);
            *(float4*)&w2v[Ht][4] = *(const float4*)(w2p + 4);
            *(float4*)&w2v[Ht][8] = *(const float4*)(w2p + 8);
        }
#pragma unroll
        for (int Ct = 0; Ct < 4; ++Ct) {
            f32x4 acc[4];
#pragma unroll
            for (int Ht = 0; Ht < 4; ++Ht) acc[Ht] = b1v[Ht];
#pragma unroll
            for (int Ht = 0; Ht < 4; ++Ht)
                acc[Ht] = __builtin_amdgcn_mfma_f32_16x16x32_bf16(afh[Ht], bfh[Ct], acc[Ht], 0, 0, 0);
#pragma unroll
            for (int Ht = 0; Ht < 4; ++Ht)
                acc[Ht] = __builtin_amdgcn_mfma_f32_16x16x32_bf16(afh[Ht], bfl[Ct], acc[Ht], 0, 0, 0);
#pragma unroll
            for (int Ht = 0; Ht < 4; ++Ht)
                acc[Ht] = __builtin_amdgcn_mfma_f32_16x16x32_bf16(afl[Ht], bfh[Ct], acc[Ht], 0, 0, 0);
            float p0 = 0.f, p1 = 0.f, p2 = 0.f;
#pragma unroll
            for (int Ht = 0; Ht < 4; ++Ht) {
#pragma unroll
                for (int r = 0; r < 4; ++r) {
                    float tv = tanh_fast(acc[Ht][r]);
                    p0 = fmaf(tv, w2v[Ht][r * 3 + 0], p0);
                    p1 = fmaf(tv, w2v[Ht][r * 3 + 1], p1);
                    p2 = fmaf(tv, w2v[Ht][r * 3 + 2], p2);
                }
            }
            float sel = (lbl[Ct] == m) ? 1.0f : 0.0f;
            out_acc[Ct][0] = fmaf(sel, p0, out_acc[Ct][0]);
            out_acc[Ct][1] = fmaf(sel, p1, out_acc[Ct][1]);
            out_acc[Ct][2] = fmaf(sel, p2, out_acc[Ct][2]);
        }
    }

    // ---- butterfly over hi-groups, then pick own cell-tile ----
#pragma unroll
    for (int Ct = 0; Ct < 4; ++Ct) {
#pragma unroll
        for (int o = 0; o < 3; ++o) {
            float v = out_acc[Ct][o];
            v += __shfl_xor(v, 16);
            v += __shfl_xor(v, 32);
            out_acc[Ct][o] = v;
        }
    }
    float f0 = sel4(out_acc[0][0], out_acc[1][0], out_acc[2][0], out_acc[3][0], hi);
    float f1 = sel4(out_acc[0][1], out_acc[1][1], out_acc[2][1], out_acc[3][1], hi);
    float f2 = sel4(out_acc[0][2], out_acc[1][2], out_acc[2][2], out_acc[3][2], hi);

    float bb0 = (label == 0) ? b2_ds[0] : (label == 1) ? b2_dr[0] : (label == 2) ? b2_rs[0] : 0.0f;
    float bb1 = (label == 0) ? b2_ds[1] : (label == 1) ? b2_dr[1] : (label == 2) ? b2_rs[1] : 0.0f;
    float bb2 = (label == 0) ? b2_ds[2] : (label == 1) ? b2_dr[2] : (label == 2) ? b2_rs[2] : 0.0f;
    f0 += bb0; f1 += bb1; f2 += bb2;

    if (cont) { f0 = hl0; f1 = hl1; f2 = hl2; }
    if (flip) { f0 = -f0; f1 = -f1; }

    if (cell < N) {
        out[(size_t)cell * 3 + 0] = f0;
        out[(size_t)cell * 3 + 1] = f1;
        out[(size_t)cell * 3 + 2] = f2;
    }
}

extern "C" void kernel_launch(void* const* d_in, const int* in_sizes, int n_in,
                              void* d_out, int out_size, void* d_ws, size_t ws_size,
                              hipStream_t stream) {
    const float* P     = (const float*)d_in[0];
    const float* U     = (const float*)d_in[1];
    const float* F     = (const float*)d_in[2];
    const float* cmax  = (const float*)d_in[3];
    const float* cmin  = (const float*)d_in[4];
    const float* W1_ds = (const float*)d_in[5];
    const float* b1_ds = (const float*)d_in[6];
    const float* W2_ds = (const float*)d_in[7];
    const float* b2_ds = (const float*)d_in[8];
    const float* W1_dr = (const float*)d_in[9];
    const float* b1_dr = (const float*)d_in[10];
    const float* W2_dr = (const float*)d_in[11];
    const float* b2_dr = (const float*)d_in[12];
    const float* W1_rs = (const float*)d_in[13];
    const float* b1_rs = (const float*)d_in[14];
    const float* W2_rs = (const float*)d_in[15];
    const float* b2_rs = (const float*)d_in[16];

    int N = in_sizes[3];
    float* out = (float*)d_out;
    uint32_t* wf = (uint32_t*)d_ws;   // 24 KB: hi 12 KB + lo 12 KB

    hipLaunchKernelGGL(prep_kernel, dim3(3), dim3(256), 0, stream,
                       W1_ds, W1_dr, W1_rs, wf);

    dim3 block(256);
    dim3 grid((N + 255) / 256);
    hipLaunchKernelGGL(riemann_mfma, grid, block, 0, stream,
                       P, U, F, cmax, cmin,
                       b1_ds, W2_ds, b2_ds,
                       b1_dr, W2_dr, b2_dr,
                       b1_rs, W2_rs, b2_rs,
                       wf, out, N);
}